// Round 3
// baseline (372.301 us; speedup 1.0000x reference)
//
#include <hip/hip_runtime.h>
#include <cstdint>
#include <cstddef>

typedef float f32x4 __attribute__((ext_vector_type(4)));
typedef short s16x8 __attribute__((ext_vector_type(8)));
typedef short s16x4 __attribute__((ext_vector_type(4)));

#define MFMA_BF16(a, b, c) __builtin_amdgcn_mfma_f32_16x16x32_bf16((a), (b), (c), 0, 0, 0)

// async global->LDS DMA, 16B/lane: lands at ldsbase + lane*16 (wave-uniform base)
#define GLD16(g, l)                                                            \
  __builtin_amdgcn_global_load_lds(                                            \
      (const __attribute__((address_space(1))) void*)(g),                      \
      (__attribute__((address_space(3))) void*)(l), 16, 0, 0)

__device__ __forceinline__ unsigned short f2bf(float f) {
  unsigned int u = __float_as_uint(f);
  u += 0x7FFFu + ((u >> 16) & 1u);
  return (unsigned short)(u >> 16);
}

__device__ __forceinline__ s16x8 cvt8(const float* __restrict__ src) {
  const float4 f0 = *(const float4*)src;
  const float4 f1 = *(const float4*)(src + 4);
  s16x8 h;
  h[0] = (short)f2bf(f0.x); h[1] = (short)f2bf(f0.y);
  h[2] = (short)f2bf(f0.z); h[3] = (short)f2bf(f0.w);
  h[4] = (short)f2bf(f1.x); h[5] = (short)f2bf(f1.y);
  h[6] = (short)f2bf(f1.z); h[7] = (short)f2bf(f1.w);
  return h;
}

// ---------------------------------------------------------------------------
// wcvt: w_qkv rows 0..1024 (Q,K proj; V-proj is dead code) fp32 -> Wcat bf16.
// ---------------------------------------------------------------------------
__global__ __launch_bounds__(256)
void wcvt(const float* __restrict__ wqkv, unsigned short* __restrict__ Wcat) {
  const size_t i = (size_t)(blockIdx.x * 256 + threadIdx.x) * 8;
  *(s16x8*)(Wcat + i) = cvt8(wqkv + i);
}

// ---------------------------------------------------------------------------
// wprod: Wcat rows 1024..1536 = W2 = w_out @ w_k  (out@w_out^T == P@(K@w_out^T),
// and K@w_out^T == x@W2^T — folds the output projection into the QKV GEMM).
// 512x512x512; 16 blocks; wk is transposed during LDS staging.
// ---------------------------------------------------------------------------
__global__ __launch_bounds__(256)
void wprod(const float* __restrict__ wqkv, const float* __restrict__ wout,
           unsigned short* __restrict__ Wcat) {
  __shared__ unsigned short As[128 * 72];  // wout rows o, contraction d on cols
  __shared__ unsigned short Bs[128 * 72];  // wk^T rows c, contraction d on cols
  const int t = threadIdx.x, lane = t & 63, wid = t >> 6;
  const int wm = wid >> 1, wn = wid & 1;
  const int nl = lane & 15, quad = lane >> 4;
  const int o0 = blockIdx.x * 128, c0 = blockIdx.y * 128;
  const int srow = t >> 3, scol = (t & 7) * 8;

  const f32x4 zero = {0.f, 0.f, 0.f, 0.f};
  f32x4 acc[4][4];
#pragma unroll
  for (int i = 0; i < 4; ++i)
#pragma unroll
    for (int j = 0; j < 4; ++j) acc[i][j] = zero;

  for (int kc = 0; kc < 512; kc += 64) {
#pragma unroll
    for (int p = 0; p < 4; ++p) {
      const int r = srow + p * 32;
      *(s16x8*)&As[r * 72 + scol] = cvt8(wout + (size_t)(o0 + r) * 512 + kc + scol);
    }
    // transpose-stage wk: Bs[c][d] = wk[d][c]; wk = wqkv rows 512..1024
#pragma unroll
    for (int p = 0; p < 4; ++p) {
      const int dloc = p * 16 + (t >> 4);
      const int cbase = (t & 15) * 8;
      const float4 f0 = *(const float4*)(wqkv + (size_t)(512 + kc + dloc) * 512 + c0 + cbase);
      const float4 f1 = *(const float4*)(wqkv + (size_t)(512 + kc + dloc) * 512 + c0 + cbase + 4);
      Bs[(cbase + 0) * 72 + dloc] = f2bf(f0.x);
      Bs[(cbase + 1) * 72 + dloc] = f2bf(f0.y);
      Bs[(cbase + 2) * 72 + dloc] = f2bf(f0.z);
      Bs[(cbase + 3) * 72 + dloc] = f2bf(f0.w);
      Bs[(cbase + 4) * 72 + dloc] = f2bf(f1.x);
      Bs[(cbase + 5) * 72 + dloc] = f2bf(f1.y);
      Bs[(cbase + 6) * 72 + dloc] = f2bf(f1.z);
      Bs[(cbase + 7) * 72 + dloc] = f2bf(f1.w);
    }
    __syncthreads();
#pragma unroll
    for (int ks = 0; ks < 2; ++ks) {
      s16x8 af[4], bf[4];
#pragma unroll
      for (int i = 0; i < 4; ++i)
        af[i] = *(const s16x8*)&As[(wm * 64 + i * 16 + nl) * 72 + ks * 32 + quad * 8];
#pragma unroll
      for (int j = 0; j < 4; ++j)
        bf[j] = *(const s16x8*)&Bs[(wn * 64 + j * 16 + nl) * 72 + ks * 32 + quad * 8];
#pragma unroll
      for (int i = 0; i < 4; ++i)
#pragma unroll
        for (int j = 0; j < 4; ++j) acc[i][j] = MFMA_BF16(af[i], bf[j], acc[i][j]);
    }
    __syncthreads();
  }
#pragma unroll
  for (int i = 0; i < 4; ++i) {
    const int o = o0 + wm * 64 + i * 16 + quad * 4;
#pragma unroll
    for (int j = 0; j < 4; ++j) {
      const int c = c0 + wn * 64 + j * 16 + nl;
#pragma unroll
      for (int r = 0; r < 4; ++r)
        Wcat[(size_t)(1024 + o + r) * 512 + c] = f2bf(acc[i][j][r]);
    }
  }
}

// ---------------------------------------------------------------------------
// gemm_qkw: [Q | K | KWT] = x(fp32, cvt in staging) @ Wcat^T. M=32768 N=1536
// K=512. XCD-aware mapping: each XCD runs all 12 N-tiles of one M-tile before
// the next -> A-tile enters one XCD's L2 once (kills the R2 133MB over-fetch).
// Q/K tiles use swapped MFMA operands (D transposed) -> 8B packed stores.
// ---------------------------------------------------------------------------
__global__ __launch_bounds__(256)
void gemm_qkw(const float* __restrict__ x, const unsigned short* __restrict__ Wcat,
              unsigned short* __restrict__ Q, unsigned short* __restrict__ K,
              unsigned short* __restrict__ KWT) {
  __shared__ unsigned short As[128 * 64];
  __shared__ unsigned short Bs[128 * 64];
  const int t = threadIdx.x, lane = t & 63, wid = t >> 6;
  const int wm = wid >> 1, wn = wid & 1;
  const int nl = lane & 15, quad = lane >> 4;
  const int sub = lane >> 3, lblk = (lane & 7) ^ sub;
  // block swizzle: xcd = l%8 (dispatch heuristic); per-XCD sequence = 12 n's
  // of one m, then next m
  const int l = blockIdx.x;
  const int xcd = l & 7, g = l >> 3;
  const int mt = (g / 12) * 8 + xcd, nt = g - (g / 12) * 12;
  const int m0 = mt * 128, n0 = nt * 128;
  const bool qk = nt < 8;
  const int srow = t >> 3, scol8 = t & 7;

  const f32x4 zero = {0.f, 0.f, 0.f, 0.f};
  f32x4 acc[4][4];
#pragma unroll
  for (int i = 0; i < 4; ++i)
#pragma unroll
    for (int j = 0; j < 4; ++j) acc[i][j] = zero;

  const unsigned short* gB = Wcat + (size_t)(n0 + wid * 32 + sub) * 512 + lblk * 8;

  for (int kc = 0; kc < 512; kc += 64) {
#pragma unroll
    for (int ii = 0; ii < 4; ++ii)
      GLD16(gB + kc + (size_t)(ii * 8) * 512, &Bs[(wid * 32 + ii * 8) * 64]);
#pragma unroll
    for (int p = 0; p < 4; ++p) {
      const int r = srow + p * 32;
      const s16x8 h = cvt8(x + (size_t)(m0 + r) * 512 + kc + scol8 * 8);
      *(s16x8*)&As[r * 64 + ((scol8 ^ (r & 7)) << 3)] = h;
    }
    __syncthreads();
    if (qk) {
#pragma unroll
      for (int ks = 0; ks < 2; ++ks) {
        s16x8 af[4], bf[4];
#pragma unroll
        for (int i = 0; i < 4; ++i)
          af[i] = *(const s16x8*)&As[(wm * 64 + i * 16 + nl) * 64 +
                                     (((ks * 4 + quad) ^ (nl & 7)) * 8)];
#pragma unroll
        for (int j = 0; j < 4; ++j)
          bf[j] = *(const s16x8*)&Bs[(wn * 64 + j * 16 + nl) * 64 +
                                     (((ks * 4 + quad) ^ (nl & 7)) * 8)];
#pragma unroll
        for (int i = 0; i < 4; ++i)
#pragma unroll
          for (int j = 0; j < 4; ++j) acc[i][j] = MFMA_BF16(bf[j], af[i], acc[i][j]);
      }
    } else {
#pragma unroll
      for (int ks = 0; ks < 2; ++ks) {
        s16x8 af[4], bf[4];
#pragma unroll
        for (int i = 0; i < 4; ++i)
          af[i] = *(const s16x8*)&As[(wm * 64 + i * 16 + nl) * 64 +
                                     (((ks * 4 + quad) ^ (nl & 7)) * 8)];
#pragma unroll
        for (int j = 0; j < 4; ++j)
          bf[j] = *(const s16x8*)&Bs[(wn * 64 + j * 16 + nl) * 64 +
                                     (((ks * 4 + quad) ^ (nl & 7)) * 8)];
#pragma unroll
        for (int i = 0; i < 4; ++i)
#pragma unroll
          for (int j = 0; j < 4; ++j) acc[i][j] = MFMA_BF16(af[i], bf[j], acc[i][j]);
      }
    }
    __syncthreads();
  }
  if (qk) {
    // swapped: D[row=n(quad*4+r), col=m(nl)] -> 4 consecutive n at fixed m
#pragma unroll
    for (int i = 0; i < 4; ++i) {
      const int m = m0 + wm * 64 + i * 16 + nl;
#pragma unroll
      for (int j = 0; j < 4; ++j) {
        const int n = n0 + wn * 64 + j * 16 + quad * 4;
        unsigned short* dst = (n < 512 ? Q : K) + (size_t)m * 512 + (n & 511);
        s16x4 h;
#pragma unroll
        for (int r = 0; r < 4; ++r) h[r] = (short)f2bf(acc[i][j][r]);
        *(s16x4*)dst = h;
      }
    }
  } else {
    // normal: D[row=seq(quad*4+r), col=o(nl)] -> 4 consecutive seq at fixed o
#pragma unroll
    for (int i = 0; i < 4; ++i) {
      const int ms = m0 + wm * 64 + i * 16 + quad * 4;
      const int b = ms >> 13, ns = ms & 8191;
#pragma unroll
      for (int j = 0; j < 4; ++j) {
        const int o = n0 - 1024 + wn * 64 + j * 16 + nl;
        s16x4 h;
#pragma unroll
        for (int r = 0; r < 4; ++r) h[r] = (short)f2bf(acc[i][j][r]);
        *(s16x4*)&KWT[(size_t)(b * 512 + o) * 8192 + ns] = h;
      }
    }
  }
}

// ---------------------------------------------------------------------------
// attn_out: per window: sim = Q·K2^T*scale, mask, softmax -> P (LDS, swizzled
// A-frag layout) -> out = P @ KWT-slice + bias. P never leaves the CU.
// 512 threads, 8 waves 2(m)x4(n). Window 0 zero-bucket: clamped loads
// neutralized pre-softmax (sim=0) and post-softmax (P cols<128 = 0).
// ---------------------------------------------------------------------------
__global__ __launch_bounds__(512)
void attn_out(const unsigned short* __restrict__ Q, const unsigned short* __restrict__ K,
              const unsigned short* __restrict__ KWT, const float* __restrict__ bias,
              float* __restrict__ out) {
  __shared__ char smem[81920];
  unsigned short* Qs = (unsigned short*)smem;              // phase1: 128x64
  unsigned short* Ks = (unsigned short*)(smem + 16384);    // phase1: 256x64
  unsigned short* Ps = (unsigned short*)smem;              // phase2: 128x256
  unsigned short* Bs2 = (unsigned short*)(smem + 65536);   // phase2: 128x64
  __shared__ float redm[512];
  __shared__ float reds[512];
  const int t = threadIdx.x;
  const int bx = blockIdx.x, b = bx >> 6, w = bx & 63;
  const int lane = t & 63, wid = t >> 6;
  const int wm = wid >> 2, wn = wid & 3;
  const int nl = lane & 15, quad = lane >> 4;
  const int sub = lane >> 3, lblk = (lane & 7) ^ sub;

  const f32x4 zero = {0.f, 0.f, 0.f, 0.f};
  f32x4 acc[4][4];
#pragma unroll
  for (int i = 0; i < 4; ++i)
#pragma unroll
    for (int j = 0; j < 4; ++j) acc[i][j] = zero;

  const unsigned short* Qb = Q + (size_t)(b * 8192 + w * 128) * 512;
  const unsigned short* Kb = K + (size_t)(b * 8192) * 512;

  for (int kc = 0; kc < 512; kc += 64) {
#pragma unroll
    for (int ii = 0; ii < 2; ++ii)
      GLD16(Qb + (size_t)(wid * 16 + ii * 8 + sub) * 512 + kc + lblk * 8,
            &Qs[(wid * 16 + ii * 8) * 64]);
#pragma unroll
    for (int ii = 0; ii < 4; ++ii) {
      int sq = w * 128 - 128 + wid * 32 + ii * 8 + sub;
      if (sq < 0) sq = 0;  // window 0: garbage, neutralized below
      GLD16(Kb + (size_t)sq * 512 + kc + lblk * 8, &Ks[(wid * 32 + ii * 8) * 64]);
    }
    __syncthreads();
#pragma unroll
    for (int ks = 0; ks < 2; ++ks) {
      s16x8 af[4], bf[4];
#pragma unroll
      for (int i = 0; i < 4; ++i)
        af[i] = *(const s16x8*)&Qs[(wm * 64 + i * 16 + nl) * 64 +
                                   (((ks * 4 + quad) ^ (nl & 7)) * 8)];
#pragma unroll
      for (int j = 0; j < 4; ++j)
        bf[j] = *(const s16x8*)&Ks[(wn * 64 + j * 16 + nl) * 64 +
                                   (((ks * 4 + quad) ^ (nl & 7)) * 8)];
#pragma unroll
      for (int i = 0; i < 4; ++i)
#pragma unroll
        for (int j = 0; j < 4; ++j) acc[i][j] = MFMA_BF16(af[i], bf[j], acc[i][j]);
    }
    __syncthreads();
  }

  const float scale = 0.04419417382415922f;  // 512^-0.5
  float rmax[4][4];
#pragma unroll
  for (int i = 0; i < 4; ++i) {
#pragma unroll
    for (int r = 0; r < 4; ++r) {
      const int row = wm * 64 + i * 16 + quad * 4 + r;
      float mx = -3.4e38f;
#pragma unroll
      for (int j = 0; j < 4; ++j) {
        const int col = wn * 64 + j * 16 + nl;
        float v = acc[i][j][r] * scale;
        if (col >= 128 && col - 128 > row) v = -3.0e38f;  // causal mask
        if (w == 0 && col < 128) v = 0.0f;                // zero bucket: sim=0
        acc[i][j][r] = v;
        mx = fmaxf(mx, v);
      }
      rmax[i][r] = mx;
    }
  }
#pragma unroll
  for (int off = 1; off < 16; off <<= 1)
#pragma unroll
    for (int i = 0; i < 4; ++i)
#pragma unroll
      for (int r = 0; r < 4; ++r)
        rmax[i][r] = fmaxf(rmax[i][r], __shfl_xor(rmax[i][r], off, 64));
  if (nl == 0) {
#pragma unroll
    for (int i = 0; i < 4; ++i)
#pragma unroll
      for (int r = 0; r < 4; ++r)
        redm[(wm * 64 + i * 16 + quad * 4 + r) * 4 + wn] = rmax[i][r];
  }
  __syncthreads();
  float rsum[4][4];
#pragma unroll
  for (int i = 0; i < 4; ++i) {
#pragma unroll
    for (int r = 0; r < 4; ++r) {
      const f32x4 mv = *(const f32x4*)&redm[(wm * 64 + i * 16 + quad * 4 + r) * 4];
      const float m = fmaxf(fmaxf(mv[0], mv[1]), fmaxf(mv[2], mv[3]));
      float s = 0.f;
#pragma unroll
      for (int j = 0; j < 4; ++j) {
        const float p = __expf(acc[i][j][r] - m);
        acc[i][j][r] = p;
        s += p;
      }
      rsum[i][r] = s;
    }
  }
#pragma unroll
  for (int off = 1; off < 16; off <<= 1)
#pragma unroll
    for (int i = 0; i < 4; ++i)
#pragma unroll
      for (int r = 0; r < 4; ++r) rsum[i][r] += __shfl_xor(rsum[i][r], off, 64);
  if (nl == 0) {
#pragma unroll
    for (int i = 0; i < 4; ++i)
#pragma unroll
      for (int r = 0; r < 4; ++r)
        reds[(wm * 64 + i * 16 + quad * 4 + r) * 4 + wn] = rsum[i][r];
  }
  __syncthreads();
  // normalize and write P -> LDS (swizzled row-major 128x256, bf16)
#pragma unroll
  for (int i = 0; i < 4; ++i) {
#pragma unroll
    for (int r = 0; r < 4; ++r) {
      const int row = wm * 64 + i * 16 + quad * 4 + r;
      const f32x4 sv = *(const f32x4*)&reds[row * 4];
      const float inv = 1.0f / (sv[0] + sv[1] + sv[2] + sv[3]);
#pragma unroll
      for (int j = 0; j < 4; ++j) {
        const int col = wn * 64 + j * 16 + nl;
        float pv = acc[i][j][r] * inv;
        if (w == 0 && col < 128) pv = 0.0f;  // zero V bucket
        const int cb = col >> 3;
        Ps[row * 256 + (((cb ^ (row & 7)) << 3) | (col & 7))] = f2bf(pv);
      }
    }
  }
  __syncthreads();

  // phase 2: out = P @ KWT-slice, K-contraction = 256 (seq), o in 4 chunks
  const int seqbase = w * 128 - 128;
#pragma unroll 1
  for (int och = 0; och < 4; ++och) {
    f32x4 acc2[4][2];
#pragma unroll
    for (int i = 0; i < 4; ++i)
#pragma unroll
      for (int j = 0; j < 2; ++j) acc2[i][j] = zero;
#pragma unroll 1
    for (int kch = 0; kch < 4; ++kch) {
#pragma unroll
      for (int ii = 0; ii < 2; ++ii) {
        const int orow = och * 128 + wid * 16 + ii * 8 + sub;
        int sq = seqbase + kch * 64 + lblk * 8;
        if (sq < 0) sq = 0;  // window 0: garbage seq hits zeroed P cols
        GLD16(KWT + (size_t)(b * 512 + orow) * 8192 + sq, &Bs2[(wid * 16 + ii * 8) * 64]);
      }
      __syncthreads();
#pragma unroll
      for (int ks = 0; ks < 2; ++ks) {
        const int kb = kch * 8 + ks * 4 + quad;
        s16x8 af[4], bf[2];
#pragma unroll
        for (int i = 0; i < 4; ++i)
          af[i] = *(const s16x8*)&Ps[(wm * 64 + i * 16 + nl) * 256 +
                                     (((kb ^ (nl & 7)) << 3))];
#pragma unroll
        for (int j = 0; j < 2; ++j)
          bf[j] = *(const s16x8*)&Bs2[(wn * 32 + j * 16 + nl) * 64 +
                                      (((ks * 4 + quad) ^ (nl & 7)) * 8)];
#pragma unroll
        for (int i = 0; i < 4; ++i)
#pragma unroll
          for (int j = 0; j < 2; ++j) acc2[i][j] = MFMA_BF16(af[i], bf[j], acc2[i][j]);
      }
      __syncthreads();
    }
#pragma unroll
    for (int i = 0; i < 4; ++i) {
      const int mrow = wm * 64 + i * 16 + quad * 4;
      float* dst = out + (size_t)(b * 8192 + w * 128 + mrow) * 512;
#pragma unroll
      for (int j = 0; j < 2; ++j) {
        const int o = och * 128 + wn * 32 + j * 16 + nl;
        const float bo = bias[o];
#pragma unroll
        for (int r = 0; r < 4; ++r) dst[(size_t)r * 512 + o] = acc2[i][j][r] + bo;
      }
    }
  }
}

extern "C" void kernel_launch(void* const* d_in, const int* in_sizes, int n_in,
                              void* d_out, int out_size, void* d_ws, size_t ws_size,
                              hipStream_t stream) {
  const float* x = (const float*)d_in[0];
  const float* w_qkv = (const float*)d_in[1];
  const float* w_out = (const float*)d_in[2];
  const float* b_out = (const float*)d_in[3];
  float* out = (float*)d_out;

  char* ws = (char*)d_ws;
  // Q @0 (32MB) | K @32MB (32MB) | KWT @64MB (32MB) | Wcat @96MB (1.5MB) = 97.5MB
  unsigned short* Q = (unsigned short*)ws;
  unsigned short* K = (unsigned short*)(ws + (size_t)33554432);
  unsigned short* KWT = (unsigned short*)(ws + (size_t)67108864);
  unsigned short* Wcat = (unsigned short*)(ws + (size_t)100663296);

  wcvt<<<dim3(256), dim3(256), 0, stream>>>(w_qkv, Wcat);
  wprod<<<dim3(4, 4), dim3(256), 0, stream>>>(w_qkv, w_out, Wcat);
  gemm_qkw<<<dim3(3072), dim3(256), 0, stream>>>(x, Wcat, Q, K, KWT);
  attn_out<<<dim3(256), dim3(512), 0, stream>>>(Q, K, KWT, b_out, out);
}

// Round 4
// 238.695 us; speedup vs baseline: 1.5597x; 1.5597x over previous
//
#include <hip/hip_runtime.h>
#include <cstdint>
#include <cstddef>

typedef float f32x4 __attribute__((ext_vector_type(4)));
typedef short s16x8 __attribute__((ext_vector_type(8)));
typedef short s16x4 __attribute__((ext_vector_type(4)));

#define MFMA_BF16(a, b, c) __builtin_amdgcn_mfma_f32_16x16x32_bf16((a), (b), (c), 0, 0, 0)

// async global->LDS DMA, 16B/lane: lands at ldsbase + lane*16 (wave-uniform base)
#define GLD16(g, l)                                                            \
  __builtin_amdgcn_global_load_lds(                                            \
      (const __attribute__((address_space(1))) void*)(g),                      \
      (__attribute__((address_space(3))) void*)(l), 16, 0, 0)

__device__ __forceinline__ unsigned short f2bf(float f) {
  unsigned int u = __float_as_uint(f);
  u += 0x7FFFu + ((u >> 16) & 1u);
  return (unsigned short)(u >> 16);
}

__device__ __forceinline__ s16x8 cvt8(const float* __restrict__ src) {
  const float4 f0 = *(const float4*)src;
  const float4 f1 = *(const float4*)(src + 4);
  s16x8 h;
  h[0] = (short)f2bf(f0.x); h[1] = (short)f2bf(f0.y);
  h[2] = (short)f2bf(f0.z); h[3] = (short)f2bf(f0.w);
  h[4] = (short)f2bf(f1.x); h[5] = (short)f2bf(f1.y);
  h[6] = (short)f2bf(f1.z); h[7] = (short)f2bf(f1.w);
  return h;
}

// ---------------------------------------------------------------------------
// cvt_bf16: x -> xb, w_qkv[0:1024] -> wb (V-proj rows dead: reference builds
// v2 from k), w_out -> wob. Memory-bound one-shot.
// ---------------------------------------------------------------------------
#define XN 16777216   // 4*8192*512
#define WQN 524288    // 1024*512
__global__ __launch_bounds__(256)
void cvt_bf16(const float* __restrict__ x, const float* __restrict__ wqkv,
              const float* __restrict__ wout, unsigned short* __restrict__ xb,
              unsigned short* __restrict__ wb, unsigned short* __restrict__ wob) {
  const size_t i = (size_t)(blockIdx.x * 256 + threadIdx.x) * 8;
  const float* src;
  unsigned short* dst;
  if (i < XN) { src = x + i; dst = xb + i; }
  else if (i < XN + WQN) { src = wqkv + (i - XN); dst = wb + (i - XN); }
  else { src = wout + (i - XN - WQN); dst = wob + (i - XN - WQN); }
  *(s16x8*)dst = cvt8(src);
}

// ---------------------------------------------------------------------------
// gemm_qk: [Q|K] = xb @ wb^T. M=32768 N=1024 K=512. m97 structure, GLD16 both
// operands, XOR-swizzled LDS. SWAPPED staging (W->As, x->Bs, block-uniform
// pointer select): D comes out transposed -> packed 8B Q/K stores.
// XCD-aware map: each XCD runs all 8 n-tiles of one m-tile consecutively.
// ---------------------------------------------------------------------------
__global__ __launch_bounds__(256)
void gemm_qk(const unsigned short* __restrict__ xb, const unsigned short* __restrict__ wb,
             unsigned short* __restrict__ Q, unsigned short* __restrict__ K) {
  __shared__ unsigned short As[128 * 64];  // W tile
  __shared__ unsigned short Bs[128 * 64];  // x tile
  const int t = threadIdx.x, lane = t & 63, wid = t >> 6;
  const int wm = wid >> 1, wn = wid & 1;
  const int nl = lane & 15, quad = lane >> 4;
  const int sub = lane >> 3, lblk = (lane & 7) ^ sub;
  const int l = blockIdx.x;
  const int xcd = l & 7, g = l >> 3;
  const int mt = (g >> 3) * 8 + xcd, nt = g & 7;
  const int m0 = mt * 128, n0 = nt * 128;

  const f32x4 zero = {0.f, 0.f, 0.f, 0.f};
  f32x4 acc[4][4];
#pragma unroll
  for (int i = 0; i < 4; ++i)
#pragma unroll
    for (int j = 0; j < 4; ++j) acc[i][j] = zero;

  const unsigned short* gX = xb + (size_t)(m0 + wid * 32 + sub) * 512 + lblk * 8;
  const unsigned short* gW = wb + (size_t)(n0 + wid * 32 + sub) * 512 + lblk * 8;

  for (int kc = 0; kc < 512; kc += 64) {
#pragma unroll
    for (int ii = 0; ii < 4; ++ii) {
      GLD16(gW + kc + (size_t)(ii * 8) * 512, &As[(wid * 32 + ii * 8) * 64]);
      GLD16(gX + kc + (size_t)(ii * 8) * 512, &Bs[(wid * 32 + ii * 8) * 64]);
    }
    __syncthreads();
#pragma unroll
    for (int ks = 0; ks < 2; ++ks) {
      s16x8 af[4], bf[4];
#pragma unroll
      for (int i = 0; i < 4; ++i)
        af[i] = *(const s16x8*)&As[(wm * 64 + i * 16 + nl) * 64 +
                                   (((ks * 4 + quad) ^ (nl & 7)) * 8)];
#pragma unroll
      for (int j = 0; j < 4; ++j)
        bf[j] = *(const s16x8*)&Bs[(wn * 64 + j * 16 + nl) * 64 +
                                   (((ks * 4 + quad) ^ (nl & 7)) * 8)];
#pragma unroll
      for (int i = 0; i < 4; ++i)
#pragma unroll
        for (int j = 0; j < 4; ++j) acc[i][j] = MFMA_BF16(af[i], bf[j], acc[i][j]);
    }
    __syncthreads();
  }
  // D rows = W-feature n (contiguous in reg r), cols = seq m -> packed stores
#pragma unroll
  for (int i = 0; i < 4; ++i) {
    const int n = n0 + wm * 64 + i * 16 + quad * 4;
    unsigned short* base = (n < 512 ? Q : K);
    const int nn = n & 511;
#pragma unroll
    for (int j = 0; j < 4; ++j) {
      const int m = m0 + wn * 64 + j * 16 + nl;
      s16x4 h;
#pragma unroll
      for (int r = 0; r < 4; ++r) h[r] = (short)f2bf(acc[i][j][r]);
      *(s16x4*)&base[(size_t)m * 512 + nn] = h;
    }
  }
}

// ---------------------------------------------------------------------------
// gemm_kwt: KWT[b][o][seq] = (K @ wob^T)^T — output projection hoisted before
// attention (out@w_out^T == P@(K2@w_out^T)). Normal operand order: D rows =
// seq (contiguous in r) -> packed 8B transposed stores. XCD-swizzled.
// ---------------------------------------------------------------------------
__global__ __launch_bounds__(256)
void gemm_kwt(const unsigned short* __restrict__ K, const unsigned short* __restrict__ wob,
              unsigned short* __restrict__ KWT) {
  __shared__ unsigned short As[128 * 64];
  __shared__ unsigned short Bs[128 * 64];
  const int t = threadIdx.x, lane = t & 63, wid = t >> 6;
  const int wm = wid >> 1, wn = wid & 1;
  const int nl = lane & 15, quad = lane >> 4;
  const int sub = lane >> 3, lblk = (lane & 7) ^ sub;
  const int l = blockIdx.x;
  const int xcd = l & 7, g = l >> 3;
  const int mt = (g >> 2) * 8 + xcd, nt = g & 3;
  const int m0 = mt * 128, n0 = nt * 128;

  const f32x4 zero = {0.f, 0.f, 0.f, 0.f};
  f32x4 acc[4][4];
#pragma unroll
  for (int i = 0; i < 4; ++i)
#pragma unroll
    for (int j = 0; j < 4; ++j) acc[i][j] = zero;

  const unsigned short* gA = K + (size_t)(m0 + wid * 32 + sub) * 512 + lblk * 8;
  const unsigned short* gB = wob + (size_t)(n0 + wid * 32 + sub) * 512 + lblk * 8;

  for (int kc = 0; kc < 512; kc += 64) {
#pragma unroll
    for (int ii = 0; ii < 4; ++ii) {
      GLD16(gA + kc + (size_t)(ii * 8) * 512, &As[(wid * 32 + ii * 8) * 64]);
      GLD16(gB + kc + (size_t)(ii * 8) * 512, &Bs[(wid * 32 + ii * 8) * 64]);
    }
    __syncthreads();
#pragma unroll
    for (int ks = 0; ks < 2; ++ks) {
      s16x8 af[4], bf[4];
#pragma unroll
      for (int i = 0; i < 4; ++i)
        af[i] = *(const s16x8*)&As[(wm * 64 + i * 16 + nl) * 64 +
                                   (((ks * 4 + quad) ^ (nl & 7)) * 8)];
#pragma unroll
      for (int j = 0; j < 4; ++j)
        bf[j] = *(const s16x8*)&Bs[(wn * 64 + j * 16 + nl) * 64 +
                                   (((ks * 4 + quad) ^ (nl & 7)) * 8)];
#pragma unroll
      for (int i = 0; i < 4; ++i)
#pragma unroll
        for (int j = 0; j < 4; ++j) acc[i][j] = MFMA_BF16(af[i], bf[j], acc[i][j]);
    }
    __syncthreads();
  }
#pragma unroll
  for (int i = 0; i < 4; ++i) {
    const int ms = m0 + wm * 64 + i * 16 + quad * 4;
    const int b = ms >> 13, ns = ms & 8191;
#pragma unroll
    for (int j = 0; j < 4; ++j) {
      const int o = n0 + wn * 64 + j * 16 + nl;
      s16x4 h;
#pragma unroll
      for (int r = 0; r < 4; ++r) h[r] = (short)f2bf(acc[i][j][r]);
      *(s16x4*)&KWT[(size_t)(b * 512 + o) * 8192 + ns] = h;
    }
  }
}

// ---------------------------------------------------------------------------
// attn64: one block = 64 Q-rows of one window (2 blocks/window -> grid 512,
// ~3 blocks/CU). Phase1: sim(64x256)=Q·K2^T, mask, softmax (rows independent
// -> no cross-block comms) -> P in LDS. Phase2: out = P @ KWT-slice + bias.
// Paired-XCD swizzle: both halves of a window land on one XCD (shared K2/KWT
// in L2). Window-0 zero bucket: sim=0 pre-softmax, P cols<128 = 0 post.
// ---------------------------------------------------------------------------
__global__ __launch_bounds__(256)
void attn64(const unsigned short* __restrict__ Q, const unsigned short* __restrict__ K,
            const unsigned short* __restrict__ KWT, const float* __restrict__ bias,
            float* __restrict__ out) {
  __shared__ char smem[49152];
  unsigned short* Qs = (unsigned short*)smem;              // phase1: 64x64  (8KB)
  unsigned short* Ks = (unsigned short*)(smem + 8192);     // phase1: 256x64 (32KB)
  unsigned short* Ps = (unsigned short*)smem;              // phase2: 64x256 (32KB)
  unsigned short* Bs2 = (unsigned short*)(smem + 32768);   // phase2: 128x64 (16KB)
  __shared__ float redm[256];
  __shared__ float reds[256];
  const int t = threadIdx.x, lane = t & 63, wid = t >> 6;
  const int wn = wid;  // 4 waves split the 256 sim cols
  const int nl = lane & 15, quad = lane >> 4;
  const int sub = lane >> 3, lblk = (lane & 7) ^ sub;
  // paired-XCD decode: bx = g*16 + half*8 + xcd
  const int bx = blockIdx.x;
  const int xcd = bx & 7, half = (bx >> 3) & 1, g = bx >> 4;
  const int wb = g * 8 + xcd, b = wb >> 6, w = wb & 63;

  const f32x4 zero = {0.f, 0.f, 0.f, 0.f};
  f32x4 acc[4][4];
#pragma unroll
  for (int i = 0; i < 4; ++i)
#pragma unroll
    for (int j = 0; j < 4; ++j) acc[i][j] = zero;

  const unsigned short* Qb = Q + (size_t)(b * 8192 + w * 128 + half * 64) * 512;
  const unsigned short* Kb = K + (size_t)(b * 8192) * 512;

  for (int kc = 0; kc < 512; kc += 64) {
#pragma unroll
    for (int ii = 0; ii < 2; ++ii)
      GLD16(Qb + (size_t)(wid * 16 + ii * 8 + sub) * 512 + kc + lblk * 8,
            &Qs[(wid * 16 + ii * 8) * 64]);
#pragma unroll
    for (int ii = 0; ii < 8; ++ii) {
      int sq = w * 128 - 128 + wid * 64 + ii * 8 + sub;
      if (sq < 0) sq = 0;  // window 0: garbage, neutralized below
      GLD16(Kb + (size_t)sq * 512 + kc + lblk * 8, &Ks[(wid * 64 + ii * 8) * 64]);
    }
    __syncthreads();
#pragma unroll
    for (int ks = 0; ks < 2; ++ks) {
      s16x8 af[4], bf[4];
#pragma unroll
      for (int i = 0; i < 4; ++i)
        af[i] = *(const s16x8*)&Qs[(i * 16 + nl) * 64 +
                                   (((ks * 4 + quad) ^ (nl & 7)) * 8)];
#pragma unroll
      for (int j = 0; j < 4; ++j)
        bf[j] = *(const s16x8*)&Ks[(wn * 64 + j * 16 + nl) * 64 +
                                   (((ks * 4 + quad) ^ (nl & 7)) * 8)];
#pragma unroll
      for (int i = 0; i < 4; ++i)
#pragma unroll
        for (int j = 0; j < 4; ++j) acc[i][j] = MFMA_BF16(af[i], bf[j], acc[i][j]);
    }
    __syncthreads();
  }

  const float scale = 0.04419417382415922f;  // 512^-0.5
  float rmax[4][4];
#pragma unroll
  for (int i = 0; i < 4; ++i) {
#pragma unroll
    for (int r = 0; r < 4; ++r) {
      const int qrow = half * 64 + i * 16 + quad * 4 + r;  // within-window row
      float mx = -3.4e38f;
#pragma unroll
      for (int j = 0; j < 4; ++j) {
        const int col = wn * 64 + j * 16 + nl;
        float v = acc[i][j][r] * scale;
        if (col >= 128 && col - 128 > qrow) v = -3.0e38f;  // causal mask
        if (w == 0 && col < 128) v = 0.0f;                 // zero bucket: sim=0
        acc[i][j][r] = v;
        mx = fmaxf(mx, v);
      }
      rmax[i][r] = mx;
    }
  }
#pragma unroll
  for (int off = 1; off < 16; off <<= 1)
#pragma unroll
    for (int i = 0; i < 4; ++i)
#pragma unroll
      for (int r = 0; r < 4; ++r)
        rmax[i][r] = fmaxf(rmax[i][r], __shfl_xor(rmax[i][r], off, 64));
  if (nl == 0) {
#pragma unroll
    for (int i = 0; i < 4; ++i)
#pragma unroll
      for (int r = 0; r < 4; ++r)
        redm[(i * 16 + quad * 4 + r) * 4 + wn] = rmax[i][r];
  }
  __syncthreads();
  float rsum[4][4];
#pragma unroll
  for (int i = 0; i < 4; ++i) {
#pragma unroll
    for (int r = 0; r < 4; ++r) {
      const f32x4 mv = *(const f32x4*)&redm[(i * 16 + quad * 4 + r) * 4];
      const float m = fmaxf(fmaxf(mv[0], mv[1]), fmaxf(mv[2], mv[3]));
      float s = 0.f;
#pragma unroll
      for (int j = 0; j < 4; ++j) {
        const float p = __expf(acc[i][j][r] - m);
        acc[i][j][r] = p;
        s += p;
      }
      rsum[i][r] = s;
    }
  }
#pragma unroll
  for (int off = 1; off < 16; off <<= 1)
#pragma unroll
    for (int i = 0; i < 4; ++i)
#pragma unroll
      for (int r = 0; r < 4; ++r) rsum[i][r] += __shfl_xor(rsum[i][r], off, 64);
  if (nl == 0) {
#pragma unroll
    for (int i = 0; i < 4; ++i)
#pragma unroll
      for (int r = 0; r < 4; ++r)
        reds[(i * 16 + quad * 4 + r) * 4 + wn] = rsum[i][r];
  }
  __syncthreads();
  // normalize, write P -> LDS (swizzled row-major 64x256 bf16)
#pragma unroll
  for (int i = 0; i < 4; ++i) {
#pragma unroll
    for (int r = 0; r < 4; ++r) {
      const int row = i * 16 + quad * 4 + r;
      const f32x4 sv = *(const f32x4*)&reds[row * 4];
      const float inv = 1.0f / (sv[0] + sv[1] + sv[2] + sv[3]);
#pragma unroll
      for (int j = 0; j < 4; ++j) {
        const int col = wn * 64 + j * 16 + nl;
        float pv = acc[i][j][r] * inv;
        if (w == 0 && col < 128) pv = 0.0f;  // zero V bucket
        const int cb = col >> 3;
        Ps[row * 256 + (((cb ^ (row & 7)) << 3) | (col & 7))] = f2bf(pv);
      }
    }
  }
  __syncthreads();

  // phase 2: out(64x512) = P(64x256) @ KWT-slice^T, o in 4 chunks of 128
  const int seqbase = w * 128 - 128;
#pragma unroll 1
  for (int och = 0; och < 4; ++och) {
    f32x4 acc2[4][2];
#pragma unroll
    for (int i = 0; i < 4; ++i)
#pragma unroll
      for (int j = 0; j < 2; ++j) acc2[i][j] = zero;
#pragma unroll 1
    for (int kch = 0; kch < 4; ++kch) {
      int sq = seqbase + kch * 64 + lblk * 8;
      if (sq < 0) sq = 0;  // window 0: garbage seq hits zeroed P cols
#pragma unroll
      for (int ii = 0; ii < 4; ++ii) {
        const int orow = och * 128 + wid * 32 + ii * 8 + sub;
        GLD16(KWT + (size_t)(b * 512 + orow) * 8192 + sq, &Bs2[(wid * 32 + ii * 8) * 64]);
      }
      __syncthreads();
#pragma unroll
      for (int ks = 0; ks < 2; ++ks) {
        const int kb = kch * 8 + ks * 4 + quad;
        s16x8 af[4], bf[2];
#pragma unroll
        for (int i = 0; i < 4; ++i)
          af[i] = *(const s16x8*)&Ps[(i * 16 + nl) * 256 + ((kb ^ (nl & 7)) << 3)];
#pragma unroll
        for (int j = 0; j < 2; ++j)
          bf[j] = *(const s16x8*)&Bs2[(wn * 32 + j * 16 + nl) * 64 +
                                      (((ks * 4 + quad) ^ (nl & 7)) * 8)];
#pragma unroll
        for (int i = 0; i < 4; ++i)
#pragma unroll
          for (int j = 0; j < 2; ++j) acc2[i][j] = MFMA_BF16(af[i], bf[j], acc2[i][j]);
      }
      __syncthreads();
    }
#pragma unroll
    for (int i = 0; i < 4; ++i) {
      const int seq = w * 128 + half * 64 + i * 16 + quad * 4;
      float* dst = out + (size_t)(b * 8192 + seq) * 512;
#pragma unroll
      for (int j = 0; j < 2; ++j) {
        const int o = och * 128 + wn * 32 + j * 16 + nl;
        const float bo = bias[o];
#pragma unroll
        for (int r = 0; r < 4; ++r) dst[(size_t)r * 512 + o] = acc2[i][j][r] + bo;
      }
    }
  }
}

extern "C" void kernel_launch(void* const* d_in, const int* in_sizes, int n_in,
                              void* d_out, int out_size, void* d_ws, size_t ws_size,
                              hipStream_t stream) {
  const float* x = (const float*)d_in[0];
  const float* w_qkv = (const float*)d_in[1];
  const float* w_out = (const float*)d_in[2];
  const float* b_out = (const float*)d_in[3];
  float* out = (float*)d_out;

  char* ws = (char*)d_ws;
  // Layout (97.5 MB, within the 112 MB proven budget):
  //   Q   @  0  (32MB)
  //   K   @ 32M (32MB)
  //   xb  @ 64M (32MB)  dead after gemm_qk
  //   KWT @ 64M (32MB)  written by gemm_kwt (aliases xb)
  //   wb  @ 96M (1MB), wob @ 97M (0.5MB)
  unsigned short* Q = (unsigned short*)ws;
  unsigned short* K = (unsigned short*)(ws + (size_t)33554432);
  unsigned short* xb = (unsigned short*)(ws + (size_t)67108864);
  unsigned short* KWT = (unsigned short*)(ws + (size_t)67108864);
  unsigned short* wb = (unsigned short*)(ws + (size_t)100663296);
  unsigned short* wob = (unsigned short*)(ws + (size_t)100663296 + 1048576);

  cvt_bf16<<<dim3(8576), dim3(256), 0, stream>>>(x, w_qkv, w_out, xb, wb, wob);
  gemm_qk<<<dim3(2048), dim3(256), 0, stream>>>(xb, wb, Q, K);
  gemm_kwt<<<dim3(1024), dim3(256), 0, stream>>>(K, wob, KWT);
  attn64<<<dim3(512), dim3(256), 0, stream>>>(Q, K, KWT, b_out, out);
}